// Round 10
// baseline (667.026 us; speedup 1.0000x reference)
//
#include <hip/hip_runtime.h>
#include <math.h>

// Problem constants (reference: x[8,2048,1024] f32, W[1024,64] f32)
#define BB 8
#define NN 2048
#define DD 1024
#define EE 64
#define CAP 64
#define NTOK (BB * NN)          // 16384
#define OUT_T_FLOATS 67108864   // 8*2048*64*64 per tensor
#define OUT_T_F4     16777216   // float4 count per tensor

// Workspace layout (bytes):
//   recs      float4[NTOK]   @ 0        {g1n, g2n, bits(i1), bits(i2 | flag<<8)}
//   frecs     float4[NTOK]   @ 262144   {g1|0, g2|0, bits(e1*64+p1 | -1), bits(e2*64+p2 | -1)}
//   dens      float[512*64]  @ 524288   per-gating-block density partials
//   lossp     float[8]       @ 655360   per-batch loss partials

// ---------------------------------------------------------------------------
// Kernel G (v7 = R2-structure, correctness-proven in the R3 run):
// lane = EXPERT, wave = 8 tokens; W staged in LDS (16 KB/chunk, b32 reads
// lane-stride-1 = 2-way = free); x read as broadcast float4 (1 line/instr,
// no TA gather). Issue model per CU: x-VMEM 65k cyc, W-LDS 47k (separate
// pipe), FMA 33k (VALU) -> co-scheduled ~40 us. vs v4 (lane=token): W-VMEM
// 65k + gather-TA 65k = 54+ us (measured 62). 512 blocks x 256 thr =
// 2 blk/CU, barriers overlap across blocks.
// ---------------------------------------------------------------------------
__global__ __launch_bounds__(256) void gating_kernel(
    const float* __restrict__ x, const float* __restrict__ W,
    float4* __restrict__ recs, float* __restrict__ dens)
{
    __shared__ float Wl[64 * 64];     // 16 KB
    __shared__ float dred[4][64];

    const int lane = threadIdx.x & 63;
    const int wave = __builtin_amdgcn_readfirstlane(threadIdx.x >> 6);
    const int tok0 = blockIdx.x * 32 + wave * 8;

    float acc[8];
#pragma unroll
    for (int t = 0; t < 8; ++t) acc[t] = 0.f;

    for (int dc = 0; dc < 16; ++dc) {
        __syncthreads();
        {   // stage W rows [dc*64, dc*64+64): 4096 floats, coalesced float4
            const float4* wg = (const float4*)(W + dc * 64 * 64);
            float4* wl = (float4*)Wl;
#pragma unroll
            for (int k = 0; k < 4; ++k)
                wl[threadIdx.x + 256 * k] = wg[threadIdx.x + 256 * k];
        }
        __syncthreads();
        // x chunk base for this wave's 8 tokens; float4 row stride = 256
        const float4* xc4 = (const float4*)(x + (size_t)tok0 * DD + dc * 64);
#pragma unroll 2
        for (int q = 0; q < 16; ++q) {
            const float w0 = Wl[(q * 4 + 0) * 64 + lane];  // lane-stride 1: free
            const float w1 = Wl[(q * 4 + 1) * 64 + lane];
            const float w2 = Wl[(q * 4 + 2) * 64 + lane];
            const float w3 = Wl[(q * 4 + 3) * 64 + lane];
#pragma unroll
            for (int t = 0; t < 8; ++t) {
                const float4 xv = xc4[t * 256 + q];  // wave-uniform broadcast
                acc[t] = fmaf(xv.x, w0, acc[t]);     // k-ascending order
                acc[t] = fmaf(xv.y, w1, acc[t]);
                acc[t] = fmaf(xv.z, w2, acc[t]);
                acc[t] = fmaf(xv.w, w3, acc[t]);
            }
        }
    }

    float densacc = 0.f;
#pragma unroll 1
    for (int t = 0; t < 8; ++t) {
        const float lv = acc[t];
        // argmax: value desc, index asc on ties (matches jnp.argmax)
        float v = lv; int bi = lane;
#pragma unroll
        for (int off = 32; off; off >>= 1) {
            float ov = __shfl_xor(v, off);
            int   oi = __shfl_xor(bi, off);
            if (ov > v || (ov == v && oi < bi)) { v = ov; bi = oi; }
        }
        const float m1 = v; const int i1 = bi;
        float v2 = (lane == i1) ? -INFINITY : lv; int b2 = lane;
#pragma unroll
        for (int off = 32; off; off >>= 1) {
            float ov = __shfl_xor(v2, off);
            int   oi = __shfl_xor(b2, off);
            if (ov > v2 || (ov == v2 && oi < b2)) { v2 = ov; b2 = oi; }
        }
        const float m2 = v2; const int i2 = b2;

        float ex = expf(lv - m1);
        float Z = ex;
#pragma unroll
        for (int off = 32; off; off >>= 1) Z += __shfl_xor(Z, off);
        float g1 = 1.0f / Z;               // p[i1]
        float g2 = expf(m2 - m1) * g1;     // p[i2]
        float den = g1 + g2 + 1e-9f;
        float g1n = g1 / den;
        float g2n = g2 / den;
        int flag = (g2n > 0.2f) ? 1 : 0;   // threshold on NORMALIZED gate_2

        densacc += ex * g1;                // p_t[lane] for density proxy

        if (lane == 0)
            recs[tok0 + t] = make_float4(g1n, g2n, __int_as_float(i1),
                                         __int_as_float(i2 | (flag << 8)));
    }

    dred[wave][lane] = densacc;
    __syncthreads();
    if (wave == 0) {
        float s = dred[0][lane] + dred[1][lane] + dred[2][lane] + dred[3][lane];
        dens[blockIdx.x * 64 + lane] = s;  // per-block partial, no atomics
    }
}

// ---------------------------------------------------------------------------
// Kernel S: ballot-based parallel rank (R3-proven version; dens indexed for
// 512 gating blocks = 64 blocks per batch).
// ---------------------------------------------------------------------------
__global__ __launch_bounds__(1024) void scan_kernel(
    const float4* __restrict__ recs, const float* __restrict__ dens,
    float4* __restrict__ frecs, float* __restrict__ lossp)
{
    const int b = blockIdx.x;
    __shared__ int hist1[32][64], pre1[32][64];
    __shared__ int hist2[32][64], pre2[32][64];
    __shared__ int base2[64];
    __shared__ float dsum[64];

    const int tid = threadIdx.x;
    const int lane = tid & 63;
    const int wave = tid >> 6;

    float4 r[2];
    int e1[2], e2[2], fl[2], rank1[2], rank2[2];
    const unsigned long long below = (1ull << lane) - 1ull;

#pragma unroll
    for (int u = 0; u < 2; ++u) {
        const int g = 2 * wave + u;
        const int tok = g * 64 + lane;
        float4 rr = recs[b * NN + tok];
        r[u] = rr;
        e1[u] = __float_as_int(rr.z);
        int i2f = __float_as_int(rr.w);
        e2[u] = i2f & 63;
        fl[u] = i2f >> 8;

        unsigned long long m = ~0ull, mv = ~0ull;
#pragma unroll
        for (int bit = 0; bit < 6; ++bit) {
            unsigned long long vt = __ballot((e1[u] >> bit) & 1);
            m  &= ((e1[u] >> bit) & 1) ? vt : ~vt;
            mv &= ((lane  >> bit) & 1) ? vt : ~vt;
        }
        rank1[u] = __popcll(m & below);
        hist1[g][lane] = __popcll(mv);

        unsigned long long fv = __ballot(fl[u]);
        m = fv; mv = fv;
#pragma unroll
        for (int bit = 0; bit < 6; ++bit) {
            unsigned long long vt = __ballot((e2[u] >> bit) & 1);
            m  &= ((e2[u] >> bit) & 1) ? vt : ~vt;
            mv &= ((lane  >> bit) & 1) ? vt : ~vt;
        }
        rank2[u] = __popcll(m & below);
        hist2[g][lane] = __popcll(mv);
    }

    if (wave == 0) {  // density sums: 64 gating blocks per batch (512 total)
        float s = 0.f;
        for (int k = 0; k < 64; ++k) s += dens[(b * 64 + k) * 64 + lane];
        dsum[lane] = s;
    }
    __syncthreads();

    if (wave == 0) {  // cross-group exclusive prefix, lane = expert
        int run = 0;
#pragma unroll
        for (int g = 0; g < 32; ++g) { pre1[g][lane] = run; run += hist1[g][lane]; }
        base2[lane] = run < CAP ? run : CAP;     // mask_1_count = min(count, cap)
        int run2 = 0;
#pragma unroll
        for (int g = 0; g < 32; ++g) { pre2[g][lane] = run2; run2 += hist2[g][lane]; }
        float v = dsum[lane] * (float)run;       // UNCAPPED count for loss
#pragma unroll
        for (int off = 32; off; off >>= 1) v += __shfl_xor(v, off);
        if (lane == 0) lossp[b] = v;
    }
    __syncthreads();

#pragma unroll
    for (int u = 0; u < 2; ++u) {
        const int g = 2 * wave + u;
        const int tok = g * 64 + lane;
        int p1 = rank1[u] + pre1[g][e1[u]];
        int k1 = p1 < CAP;
        int p2 = rank2[u] + pre2[g][e2[u]] + base2[e2[u]];
        int k2 = fl[u] && (p2 < CAP);
        float4 fr;
        fr.x = k1 ? r[u].x : 0.f;
        fr.y = k2 ? r[u].y : 0.f;
        fr.z = __int_as_float(k1 ? (e1[u] * CAP + p1) : -1);
        fr.w = __int_as_float(k2 ? (e2[u] * CAP + p2) : -1);
        frecs[b * NN + tok] = fr;
    }
}

// ---------------------------------------------------------------------------
// Kernel F (v1, unchanged from R6 — ~95 us vs 85 us write floor).
// ---------------------------------------------------------------------------
__global__ __launch_bounds__(256) void fill_kernel(
    const float4* __restrict__ frecs, const float* __restrict__ lossp,
    float* __restrict__ out)
{
    const int tid = blockIdx.x * 256 + threadIdx.x;   // 0 .. 16777215
    const int token = tid >> 10;
    const int e  = (tid >> 4) & 63;
    const int c4 = tid & 15;
    float4 r = frecs[token];   // broadcast across 1024 threads -> L1 hit

    float cx = 0.f, cy = 0.f, cz = 0.f, cw = 0.f;
    float dx = 0.f, dy = 0.f, dz = 0.f, dw = 0.f;

    int p1 = __float_as_int(r.z);
    if (p1 >= 0 && (p1 >> 6) == e && ((p1 >> 2) & 15) == c4) {
        int cc = p1 & 3;
        if      (cc == 0) { cx = r.x; dx = 1.f; }
        else if (cc == 1) { cy = r.x; dy = 1.f; }
        else if (cc == 2) { cz = r.x; dz = 1.f; }
        else              { cw = r.x; dw = 1.f; }
    }
    int p2 = __float_as_int(r.w);
    if (p2 >= 0 && (p2 >> 6) == e && ((p2 >> 2) & 15) == c4) {
        int cc = p2 & 3;
        if      (cc == 0) { cx = r.y; dx = 1.f; }
        else if (cc == 1) { cy = r.y; dy = 1.f; }
        else if (cc == 2) { cz = r.y; dz = 1.f; }
        else              { cw = r.y; dw = 1.f; }
    }

    float4* o4 = (float4*)out;
    o4[tid]             = make_float4(dx, dy, dz, dw);   // dispatch
    o4[tid + OUT_T_F4]  = make_float4(cx, cy, cz, cw);   // combine

    if (tid == 0) {
        float s = 0.f;
        for (int k = 0; k < 8; ++k) s += lossp[k];
        // loss = sum_b lossp[b] * e^2 / (b*e*n^2) = s / 524288
        out[2 * (size_t)OUT_T_FLOATS] = s * (1.0f / 524288.0f);
    }
}

extern "C" void kernel_launch(void* const* d_in, const int* in_sizes, int n_in,
                              void* d_out, int out_size, void* d_ws, size_t ws_size,
                              hipStream_t stream)
{
    const float* x = (const float*)d_in[0];
    const float* W = (const float*)d_in[1];
    float* out = (float*)d_out;
    char* ws = (char*)d_ws;

    float4* recs  = (float4*)(ws);
    float4* frecs = (float4*)(ws + 262144);
    float*  dens  = (float*)(ws + 524288);   // 512*64 floats
    float*  lossp = (float*)(ws + 655360);

    gating_kernel<<<512, 256, 0, stream>>>(x, W, recs, dens);
    scan_kernel<<<8, 1024, 0, stream>>>(recs, dens, frecs, lossp);
    fill_kernel<<<65536, 256, 0, stream>>>(frecs, lossp, out);
}

// Round 11
// 658.203 us; speedup vs baseline: 1.0134x; 1.0134x over previous
//
#include <hip/hip_runtime.h>
#include <math.h>

// Problem constants (reference: x[8,2048,1024] f32, W[1024,64] f32)
#define BB 8
#define NN 2048
#define DD 1024
#define EE 64
#define CAP 64
#define NTOK (BB * NN)          // 16384
#define OUT_T_FLOATS 67108864   // 8*2048*64*64 per tensor
#define OUT_T_F4     16777216   // float4 count per tensor

// Workspace layout (bytes):
//   recs      float4[NTOK]   @ 0        {g1n, g2n, bits(i1), bits(i2 | flag<<8)}
//   frecs     float4[NTOK]   @ 262144   {g1|0, g2|0, bits(e1*64+p1 | -1), bits(e2*64+p2 | -1)}
//   dens      float[256*64]  @ 524288   per-gating-block density partials
//   lossp     float[8]       @ 589824   per-batch loss partials

// ---------------------------------------------------------------------------
// Kernel G (v8): thread-level W reuse + 4-lane-coalesced x gather.
// Issue economics of all prior variants: v4 = W-issue 27us + gather-TA 27us
// (measured 62); v5/v6 added LDS staging at 1 blk/CU (106-114); v7 paid
// broadcast x-issue 27us at 2 waves/SIMD (117). v8 cuts BOTH v4 bills:
//   16 waves = 2 k-halves (kh) x 8 expert-octets (eg).
//   lane = (r = token 0..15, q = k-interleave 0..3).
//   thread: 4 tokens (r+16*tt) x 8 experts x 128 k-elems -> acc[4][8].
//   x: same-r lanes (q=0..3) read 4 consecutive f4 = 64 B line -> 16
//      lines/instr (4x less TA); 128 x-loads/thread.
//   W: one W f4 feeds 4 tokens -> 256 W-loads/thread (4x less issue);
//      4 distinct addrs/instr, L2-resident.
// Reduction: q via 2 shfl_xor (deterministic), kh via LDS (stride-68 rows:
// 16B-aligned, 2-way banks = free). No staging barriers.
// ---------------------------------------------------------------------------
__global__ __launch_bounds__(1024, 4) void gating_kernel(
    const float* __restrict__ x, const float* __restrict__ W,
    float4* __restrict__ recs, float* __restrict__ dens)
{
    __shared__ float lg[2][64][68];     // [kh][token][expert(+pad)] 34.8 KB
    __shared__ float dred[4][64];

    const int tid  = threadIdx.x;
    const int lane = tid & 63;
    const int wave = __builtin_amdgcn_readfirstlane(tid >> 6);
    const int kh   = wave & 1;          // k-half (512 k)
    const int eg   = wave >> 1;         // 8-expert octet
    const int r    = lane & 15;         // token-in-group
    const int q    = lane >> 4;         // k-interleave
    const int tok0 = blockIdx.x * 64;

    float acc[4][8];
#pragma unroll
    for (int tt = 0; tt < 4; ++tt)
#pragma unroll
        for (int j = 0; j < 8; ++j) acc[tt][j] = 0.f;

    // x row pointers (f4 units), pre-offset by this thread's column phase
    const float4* xr[4];
#pragma unroll
    for (int tt = 0; tt < 4; ++tt)
        xr[tt] = (const float4*)(x + (size_t)(tok0 + tt * 16 + r) * DD)
                 + kh * 128 + q;
    const float* wcol = W + eg * 8;     // + k*64 per k-element

#pragma unroll 2
    for (int c = 0; c < 32; ++c) {
        float4 xv[4];
#pragma unroll
        for (int tt = 0; tt < 4; ++tt) xv[tt] = xr[tt][c * 4];
        const int k0 = (kh * 128 + c * 4 + q) * 4;   // k-element base
#pragma unroll
        for (int kk = 0; kk < 4; ++kk) {
            const float* wrow = wcol + (size_t)(k0 + kk) * EE;
            const float4 w0 = *(const float4*)(wrow);
            const float4 w1 = *(const float4*)(wrow + 4);
#pragma unroll
            for (int tt = 0; tt < 4; ++tt) {
                const float xs = ((const float*)&xv[tt])[kk];
                acc[tt][0] = fmaf(xs, w0.x, acc[tt][0]);   // k ascending per acc
                acc[tt][1] = fmaf(xs, w0.y, acc[tt][1]);
                acc[tt][2] = fmaf(xs, w0.z, acc[tt][2]);
                acc[tt][3] = fmaf(xs, w0.w, acc[tt][3]);
                acc[tt][4] = fmaf(xs, w1.x, acc[tt][4]);
                acc[tt][5] = fmaf(xs, w1.y, acc[tt][5]);
                acc[tt][6] = fmaf(xs, w1.z, acc[tt][6]);
                acc[tt][7] = fmaf(xs, w1.w, acc[tt][7]);
            }
        }
    }

    // ---- q-reduction (lanes 16 apart hold same (token, expert) partials)
#pragma unroll
    for (int tt = 0; tt < 4; ++tt)
#pragma unroll
        for (int j = 0; j < 8; ++j) {
            float v = acc[tt][j];
            v += __shfl_xor(v, 16);
            v += __shfl_xor(v, 32);
            acc[tt][j] = v;
        }
    if (q == 0) {
#pragma unroll
        for (int tt = 0; tt < 4; ++tt) {
            // stride 68 rows: 16B-aligned (68*4B = 272 = 17*16); banks 2-way
            *(float4*)&lg[kh][tt * 16 + r][eg * 8]     =
                make_float4(acc[tt][0], acc[tt][1], acc[tt][2], acc[tt][3]);
            *(float4*)&lg[kh][tt * 16 + r][eg * 8 + 4] =
                make_float4(acc[tt][4], acc[tt][5], acc[tt][6], acc[tt][7]);
        }
    }
    __syncthreads();

    // ---- epilogue: waves 0-3, wave w handles tokens [16w,16w+16); lane = expert
    if (wave < 4) {
        const int t0 = wave * 16;
        float densacc = 0.f;
#pragma unroll 1
        for (int ti = 0; ti < 16; ++ti) {
            const int t = t0 + ti;
            const float lv = lg[0][t][lane] + lg[1][t][lane];  // stride-1: free

            // argmax: value desc, index asc on ties (matches jnp.argmax)
            float v = lv; int bi = lane;
#pragma unroll
            for (int off = 32; off; off >>= 1) {
                float ov = __shfl_xor(v, off);
                int   oi = __shfl_xor(bi, off);
                if (ov > v || (ov == v && oi < bi)) { v = ov; bi = oi; }
            }
            const float m1 = v; const int i1 = bi;
            float v2 = (lane == i1) ? -INFINITY : lv; int b2 = lane;
#pragma unroll
            for (int off = 32; off; off >>= 1) {
                float ov = __shfl_xor(v2, off);
                int   oi = __shfl_xor(b2, off);
                if (ov > v2 || (ov == v2 && oi < b2)) { v2 = ov; b2 = oi; }
            }
            const float m2 = v2; const int i2 = b2;

            float ex = expf(lv - m1);
            float Z = ex;
#pragma unroll
            for (int off = 32; off; off >>= 1) Z += __shfl_xor(Z, off);
            float g1 = 1.0f / Z;               // p[i1]
            float g2 = expf(m2 - m1) * g1;     // p[i2]
            float den = g1 + g2 + 1e-9f;
            float g1n = g1 / den;
            float g2n = g2 / den;
            int flag = (g2n > 0.2f) ? 1 : 0;   // threshold on NORMALIZED gate_2

            densacc += ex * g1;                // p_t[lane] for density proxy

            if (lane == 0)
                recs[blockIdx.x * 64 + t] =
                    make_float4(g1n, g2n, __int_as_float(i1),
                                __int_as_float(i2 | (flag << 8)));
        }
        dred[wave][lane] = densacc;
    }
    __syncthreads();
    if (tid < 64) {
        float s = dred[0][tid] + dred[1][tid] + dred[2][tid] + dred[3][tid];
        dens[blockIdx.x * 64 + tid] = s;       // per-block partial, no atomics
    }
}

// ---------------------------------------------------------------------------
// Kernel S: ballot-based parallel rank (R6 version: 32 gating blocks/batch).
// ---------------------------------------------------------------------------
__global__ __launch_bounds__(1024) void scan_kernel(
    const float4* __restrict__ recs, const float* __restrict__ dens,
    float4* __restrict__ frecs, float* __restrict__ lossp)
{
    const int b = blockIdx.x;
    __shared__ int hist1[32][64], pre1[32][64];
    __shared__ int hist2[32][64], pre2[32][64];
    __shared__ int base2[64];
    __shared__ float dsum[64];

    const int tid = threadIdx.x;
    const int lane = tid & 63;
    const int wave = tid >> 6;

    float4 r[2];
    int e1[2], e2[2], fl[2], rank1[2], rank2[2];
    const unsigned long long below = (1ull << lane) - 1ull;

#pragma unroll
    for (int u = 0; u < 2; ++u) {
        const int g = 2 * wave + u;
        const int tok = g * 64 + lane;
        float4 rr = recs[b * NN + tok];
        r[u] = rr;
        e1[u] = __float_as_int(rr.z);
        int i2f = __float_as_int(rr.w);
        e2[u] = i2f & 63;
        fl[u] = i2f >> 8;

        unsigned long long m = ~0ull, mv = ~0ull;
#pragma unroll
        for (int bit = 0; bit < 6; ++bit) {
            unsigned long long vt = __ballot((e1[u] >> bit) & 1);
            m  &= ((e1[u] >> bit) & 1) ? vt : ~vt;
            mv &= ((lane  >> bit) & 1) ? vt : ~vt;
        }
        rank1[u] = __popcll(m & below);
        hist1[g][lane] = __popcll(mv);

        unsigned long long fv = __ballot(fl[u]);
        m = fv; mv = fv;
#pragma unroll
        for (int bit = 0; bit < 6; ++bit) {
            unsigned long long vt = __ballot((e2[u] >> bit) & 1);
            m  &= ((e2[u] >> bit) & 1) ? vt : ~vt;
            mv &= ((lane  >> bit) & 1) ? vt : ~vt;
        }
        rank2[u] = __popcll(m & below);
        hist2[g][lane] = __popcll(mv);
    }

    if (wave == 0) {  // density sums: 32 gating blocks per batch
        float s = 0.f;
        for (int k = 0; k < 32; ++k) s += dens[(b * 32 + k) * 64 + lane];
        dsum[lane] = s;
    }
    __syncthreads();

    if (wave == 0) {  // cross-group exclusive prefix, lane = expert
        int run = 0;
#pragma unroll
        for (int g = 0; g < 32; ++g) { pre1[g][lane] = run; run += hist1[g][lane]; }
        base2[lane] = run < CAP ? run : CAP;     // mask_1_count = min(count, cap)
        int run2 = 0;
#pragma unroll
        for (int g = 0; g < 32; ++g) { pre2[g][lane] = run2; run2 += hist2[g][lane]; }
        float v = dsum[lane] * (float)run;       // UNCAPPED count for loss
#pragma unroll
        for (int off = 32; off; off >>= 1) v += __shfl_xor(v, off);
        if (lane == 0) lossp[b] = v;
    }
    __syncthreads();

#pragma unroll
    for (int u = 0; u < 2; ++u) {
        const int g = 2 * wave + u;
        const int tok = g * 64 + lane;
        int p1 = rank1[u] + pre1[g][e1[u]];
        int k1 = p1 < CAP;
        int p2 = rank2[u] + pre2[g][e2[u]] + base2[e2[u]];
        int k2 = fl[u] && (p2 < CAP);
        float4 fr;
        fr.x = k1 ? r[u].x : 0.f;
        fr.y = k2 ? r[u].y : 0.f;
        fr.z = __int_as_float(k1 ? (e1[u] * CAP + p1) : -1);
        fr.w = __int_as_float(k2 ? (e2[u] * CAP + p2) : -1);
        frecs[b * NN + tok] = fr;
    }
}

// ---------------------------------------------------------------------------
// Kernel F (v1, unchanged from R6 — ~95 us vs 85 us write floor).
// ---------------------------------------------------------------------------
__global__ __launch_bounds__(256) void fill_kernel(
    const float4* __restrict__ frecs, const float* __restrict__ lossp,
    float* __restrict__ out)
{
    const int tid = blockIdx.x * 256 + threadIdx.x;   // 0 .. 16777215
    const int token = tid >> 10;
    const int e  = (tid >> 4) & 63;
    const int c4 = tid & 15;
    float4 r = frecs[token];   // broadcast across 1024 threads -> L1 hit

    float cx = 0.f, cy = 0.f, cz = 0.f, cw = 0.f;
    float dx = 0.f, dy = 0.f, dz = 0.f, dw = 0.f;

    int p1 = __float_as_int(r.z);
    if (p1 >= 0 && (p1 >> 6) == e && ((p1 >> 2) & 15) == c4) {
        int cc = p1 & 3;
        if      (cc == 0) { cx = r.x; dx = 1.f; }
        else if (cc == 1) { cy = r.x; dy = 1.f; }
        else if (cc == 2) { cz = r.x; dz = 1.f; }
        else              { cw = r.x; dw = 1.f; }
    }
    int p2 = __float_as_int(r.w);
    if (p2 >= 0 && (p2 >> 6) == e && ((p2 >> 2) & 15) == c4) {
        int cc = p2 & 3;
        if      (cc == 0) { cx = r.y; dx = 1.f; }
        else if (cc == 1) { cy = r.y; dy = 1.f; }
        else if (cc == 2) { cz = r.y; dz = 1.f; }
        else              { cw = r.y; dw = 1.f; }
    }

    float4* o4 = (float4*)out;
    o4[tid]             = make_float4(dx, dy, dz, dw);   // dispatch
    o4[tid + OUT_T_F4]  = make_float4(cx, cy, cz, cw);   // combine

    if (tid == 0) {
        float s = 0.f;
        for (int k = 0; k < 8; ++k) s += lossp[k];
        // loss = sum_b lossp[b] * e^2 / (b*e*n^2) = s / 524288
        out[2 * (size_t)OUT_T_FLOATS] = s * (1.0f / 524288.0f);
    }
}

extern "C" void kernel_launch(void* const* d_in, const int* in_sizes, int n_in,
                              void* d_out, int out_size, void* d_ws, size_t ws_size,
                              hipStream_t stream)
{
    const float* x = (const float*)d_in[0];
    const float* W = (const float*)d_in[1];
    float* out = (float*)d_out;
    char* ws = (char*)d_ws;

    float4* recs  = (float4*)(ws);
    float4* frecs = (float4*)(ws + 262144);
    float*  dens  = (float*)(ws + 524288);   // 256*64 floats
    float*  lossp = (float*)(ws + 589824);

    gating_kernel<<<256, 1024, 0, stream>>>(x, W, recs, dens);
    scan_kernel<<<8, 1024, 0, stream>>>(recs, dens, frecs, lossp);
    fill_kernel<<<65536, 256, 0, stream>>>(frecs, lossp, out);
}